// Round 9
// baseline (33.546 us; speedup 1.0000x reference)
//
#include <hip/hip_runtime.h>
#include <hip/hip_bf16.h>
#include <math.h>

#define BB 8
#define BS 65536  // 256*256

typedef __attribute__((ext_vector_type(8))) short short8v;
typedef __attribute__((ext_vector_type(4))) float f32x4;
typedef unsigned short u16;
typedef unsigned int u32;
typedef __attribute__((address_space(1))) const void gv_t;
typedef __attribute__((address_space(3))) void lv_t;

__device__ __forceinline__ u16 f2bf(float v) {
  __hip_bfloat16 h = __float2bfloat16(v);
  return *reinterpret_cast<u16*>(&h);
}

// MFMA LDS tiles: [32 rows][64 k] bf16 (4 KiB), row = 128 B = 8 chunks x 16 B.
// XOR swizzle cs = c ^ (r&7), applied identically on write and read (#21).
__device__ __forceinline__ short8v frag(const u16* lds, int rb, int sk,
                                        int lane) {
  int r = rb * 16 + (lane & 15);
  int c = sk * 4 + (lane >> 4);
  int cs = c ^ (r & 7);
  return *(const short8v*)(lds + r * 64 + cs * 8);
}

// ---------------------------------------------------------------------------
// D1: merged projection GEMMs, batch-affine (b = blockIdx & 7 -> XCD b).
//  L2p[b][n][dd] = |0.4a[dd]|*( sum_f x[f,n] W[dd,f] + b_lin[dd] )   (f32)
//  R2p[b][d2][n] = packed bf16 pair { R'(2*d2, n), R'(2*d2+1, n) }
//      where R'(dd,n) = |0.4a[dd]| * sum_f x[f,n] W[dd,256+f]
// 512 blocks x 256 thr; block = (b, n0 = (t>>3)*32, dd0 = (t&7)*32).
// ---------------------------------------------------------------------------
__global__ __launch_bounds__(256) void d1_proj(
    const float* __restrict__ x, const float* __restrict__ W,
    const float* __restrict__ b_lin, const float* __restrict__ a,
    float* __restrict__ L2p, u32* __restrict__ R2p) {
  __shared__ float xf[64][33];
  __shared__ u16 XT[32 * 64], B1[32 * 64], B2[32 * 64];
  const int bk = blockIdx.x, tid = threadIdx.x;
  const int b = bk & 7, t = bk >> 3;
  const int n0 = (t >> 3) * 32, dd0 = (t & 7) * 32;
  const int lane = tid & 63, wid = tid >> 6;
  const int nh = wid >> 1, dh = wid & 1;
  const float* xb = x + (size_t)b * BS;

  const int r8 = tid >> 5, c32 = tid & 31;   // x-tile staging coords
  const int rw = tid >> 3, cw = tid & 7;     // W / XT staging coords

  f32x4 accL = f32x4{0.f, 0.f, 0.f, 0.f};
  f32x4 accR = f32x4{0.f, 0.f, 0.f, 0.f};

  for (int ks = 0; ks < 4; ++ks) {
    // P1: global loads -> regs, x -> LDS f32
    float xr[8];
#pragma unroll
    for (int it = 0; it < 8; ++it)
      xr[it] = xb[(size_t)(ks * 64 + it * 8 + r8) * 256 + n0 + c32];
    float4 wa0 = *(const float4*)&W[(size_t)(dd0 + rw) * 512 + ks * 64 + cw * 8];
    float4 wa1 = *(const float4*)&W[(size_t)(dd0 + rw) * 512 + ks * 64 + cw * 8 + 4];
    float4 wb0 = *(const float4*)&W[(size_t)(dd0 + rw) * 512 + 256 + ks * 64 + cw * 8];
    float4 wb1 = *(const float4*)&W[(size_t)(dd0 + rw) * 512 + 256 + ks * 64 + cw * 8 + 4];
#pragma unroll
    for (int it = 0; it < 8; ++it) xf[it * 8 + r8][c32] = xr[it];
    __syncthreads();
    // P2: XT (transposed x, bf16, swizzled) + B1/B2 (W rows, bf16, swizzled)
    {
      u16 o[8];
#pragma unroll
      for (int e = 0; e < 8; ++e) o[e] = f2bf(xf[cw * 8 + e][rw]);
      *(short8v*)&XT[rw * 64 + ((cw ^ (rw & 7)) * 8)] = *(const short8v*)o;
      u16 o1[8] = {f2bf(wa0.x), f2bf(wa0.y), f2bf(wa0.z), f2bf(wa0.w),
                   f2bf(wa1.x), f2bf(wa1.y), f2bf(wa1.z), f2bf(wa1.w)};
      *(short8v*)&B1[rw * 64 + ((cw ^ (rw & 7)) * 8)] = *(const short8v*)o1;
      u16 o2[8] = {f2bf(wb0.x), f2bf(wb0.y), f2bf(wb0.z), f2bf(wb0.w),
                   f2bf(wb1.x), f2bf(wb1.y), f2bf(wb1.z), f2bf(wb1.w)};
      *(short8v*)&B2[rw * 64 + ((cw ^ (rw & 7)) * 8)] = *(const short8v*)o2;
    }
    __syncthreads();
    // P3: MFMA
#pragma unroll
    for (int sk = 0; sk < 2; ++sk) {
      short8v xa = frag(XT, nh, sk, lane);
      short8v w1 = frag(B1, dh, sk, lane);
      short8v w2 = frag(B2, dh, sk, lane);
      accL = __builtin_amdgcn_mfma_f32_16x16x32_bf16(xa, w1, accL, 0, 0, 0);
      accR = __builtin_amdgcn_mfma_f32_16x16x32_bf16(w2, xa, accR, 0, 0, 0);
    }
  }

  // epilogue: L2p[n][dd] (f32)
  {
    int ddc = dd0 + dh * 16 + (lane & 15);
    float c2 = fabsf(0.4f * a[ddc]);
    float bl = b_lin[ddc];
    int nr = n0 + nh * 16 + ((lane >> 4) << 2);
#pragma unroll
    for (int q = 0; q < 4; ++q)
      L2p[(size_t)b * BS + (size_t)(nr + q) * 256 + ddc] = c2 * (accL[q] + bl);
  }
  // epilogue: R2p packed bf16 pairs [d2][n]
  {
    int nc = n0 + nh * 16 + (lane & 15);
    int ddr = dd0 + dh * 16 + ((lane >> 4) << 2);  // multiple of 4
    float r0 = fabsf(0.4f * a[ddr + 0]) * accR[0];
    float r1 = fabsf(0.4f * a[ddr + 1]) * accR[1];
    float r2 = fabsf(0.4f * a[ddr + 2]) * accR[2];
    float r3 = fabsf(0.4f * a[ddr + 3]) * accR[3];
    u32 p01 = (u32)f2bf(r0) | ((u32)f2bf(r1) << 16);
    u32 p23 = (u32)f2bf(r2) | ((u32)f2bf(r3) << 16);
    u32* Rp = R2p + (size_t)b * 32768;
    Rp[(size_t)(ddr >> 1) * 256 + nc] = p01;
    Rp[(size_t)((ddr >> 1) + 1) * 256 + nc] = p23;
  }
}

// ---------------------------------------------------------------------------
// D23: fused scores+softmax+output. 256 blocks x 512 thr, batch-affine.
// Phase A (= R8 d2, barrier-free): e[i,j] = 1.5*sum sgn*R + bias +
//   sum_d sgn[d]*|L2p[i,d]+R[d,j]|, mask, softmax over j.
//   attn rows i0..i0+7 -> LDS PlB bf16 [16][264] (rows 8..15 zero n-padding).
// Phase B (per-wave, barrier-free): out[:,i0..i0+7] = sigmoid(x . P^T) + x.
//   Wave w owns f-rows w*32..+31: A-frags reg-staged from x (f32->bf16, no
//   LDS), B-frags = PlB rows (n = lane&15, k = j contiguous — the D3-verified
//   B-operand layout). 16 MFMA/wave; masked writes col<8.
// ---------------------------------------------------------------------------
__global__ __launch_bounds__(512) void d23_fused(
    const u32* __restrict__ R2p, const float* __restrict__ L2p,
    const float* __restrict__ a, const int* __restrict__ adj,
    const float* __restrict__ bias, const float* __restrict__ x,
    float* __restrict__ out) {
  __shared__ float4 Lq[2][256];   // [ih][d]: rows i0+4ih..+3 at col d
  __shared__ float2 sS2[128];     // sign pairs (sgn[2d2], sgn[2d2+1])
  __shared__ float redm[8][4], reds[8][4];
  __shared__ u16 PlB[16][264];    // attn bf16; stride 264 u16 = 528 B (16B mult)
  const int t = threadIdx.x, j = t & 255, ih = t >> 8;
  const int bk = blockIdx.x, b = bk & 7, i0 = (bk >> 3) * 8;
  const u32* Rb = R2p + (size_t)b * 32768;

  // zero PlB n-padding rows 8..15 (cols 0..255)
  {
    int zr = 8 + (t >> 6), zc = (t & 63) * 4;
    *(uint2*)&PlB[zr][zc] = make_uint2(0u, 0u);
  }
  // early mask/bias loads (consumed after the d-loop)
  int adjv[4];
  float biasv[4];
#pragma unroll
  for (int ii = 0; ii < 4; ++ii) {
    int row = i0 + ih * 4 + ii;
    adjv[ii] = adj[(size_t)b * BS + (size_t)row * 256 + j];
    biasv[ii] = bias[row * 256 + j];
  }
  // L rows + packed sign pairs -> LDS
  {
    const float* Lb = L2p + (size_t)b * BS + (size_t)(i0 + ih * 4) * 256;
    Lq[ih][j] = make_float4(Lb[j], Lb[256 + j], Lb[512 + j], Lb[768 + j]);
    if (t < 128) {
      float2 av = *(const float2*)&a[2 * t];
      sS2[t] = make_float2(av.x >= 0.f ? 1.f : -1.f, av.y >= 0.f ? 1.f : -1.f);
    }
  }
  __syncthreads();

  float e0 = 0.f, e1 = 0.f, e2 = 0.f, e3 = 0.f, srj = 0.f;
#pragma unroll 8
  for (int d2 = 0; d2 < 128; ++d2) {
    u32 u = Rb[d2 * 256 + j];                       // coalesced dword, L2-hot
    float rv0 = __uint_as_float(u << 16);           // low bf16  = d = 2*d2
    float rv1 = __uint_as_float(u & 0xffff0000u);   // high bf16 = 2*d2+1
    float2 ss = sS2[d2];
    float4 lq0 = Lq[ih][2 * d2];
    float4 lq1 = Lq[ih][2 * d2 + 1];
    srj = fmaf(ss.x, rv0, srj);
    srj = fmaf(ss.y, rv1, srj);
    e0 = fmaf(ss.x, fabsf(lq0.x + rv0), e0);
    e1 = fmaf(ss.x, fabsf(lq0.y + rv0), e1);
    e2 = fmaf(ss.x, fabsf(lq0.z + rv0), e2);
    e3 = fmaf(ss.x, fabsf(lq0.w + rv0), e3);
    e0 = fmaf(ss.y, fabsf(lq1.x + rv1), e0);
    e1 = fmaf(ss.y, fabsf(lq1.y + rv1), e1);
    e2 = fmaf(ss.y, fabsf(lq1.z + rv1), e2);
    e3 = fmaf(ss.y, fabsf(lq1.w + rv1), e3);
  }

  float ev[4] = {e0, e1, e2, e3};
  const float sbase = 1.5f * srj;
  const float NEG_INF = -__builtin_inff();
#pragma unroll
  for (int ii = 0; ii < 4; ++ii) {
    ev[ii] += sbase + biasv[ii];
    ev[ii] = (adjv[ii] == 0) ? NEG_INF : ev[ii];
  }
  const int wid = t >> 6, lane = t & 63, wb = ih * 4;
#pragma unroll
  for (int ii = 0; ii < 4; ++ii) {
    float v = ev[ii];
#pragma unroll
    for (int off = 32; off >= 1; off >>= 1) v = fmaxf(v, __shfl_xor(v, off, 64));
    if (lane == 0) redm[wid][ii] = v;
  }
  __syncthreads();
  float p4[4];
#pragma unroll
  for (int ii = 0; ii < 4; ++ii) {
    float m = fmaxf(fmaxf(redm[wb][ii], redm[wb + 1][ii]),
                    fmaxf(redm[wb + 2][ii], redm[wb + 3][ii]));
    p4[ii] = (m == NEG_INF) ? 1.f : __expf(ev[ii] - m);
  }
#pragma unroll
  for (int ii = 0; ii < 4; ++ii) {
    float v = p4[ii];
#pragma unroll
    for (int off = 32; off >= 1; off >>= 1) v += __shfl_xor(v, off, 64);
    if (lane == 0) reds[wid][ii] = v;
  }
  __syncthreads();
#pragma unroll
  for (int ii = 0; ii < 4; ++ii) {
    float ssum = reds[wb][ii] + reds[wb + 1][ii] + reds[wb + 2][ii] +
                 reds[wb + 3][ii];
    PlB[ih * 4 + ii][j] = f2bf(p4[ii] / ssum);
  }
  __syncthreads();  // PlB (incl. zero rows) visible to all waves

  // ---------------- Phase B: out columns i0..i0+7 ----------------
  {
    const int fw = wid * 32;               // this wave's 32 f-rows
    const float* xb2 = x + (size_t)b * BS;
    const int r0 = lane & 15, hk = (lane >> 4) * 8;
    f32x4 acc0 = f32x4{0.f, 0.f, 0.f, 0.f};
    f32x4 acc1 = f32x4{0.f, 0.f, 0.f, 0.f};
#pragma unroll
    for (int step = 0; step < 8; ++step) {
      int kk = step * 32 + hk;
      const float* p0 = xb2 + (size_t)(fw + r0) * 256 + kk;
      const float* p1 = xb2 + (size_t)(fw + r0 + 16) * 256 + kk;
      float4 a0 = *(const float4*)p0;
      float4 a1 = *(const float4*)(p0 + 4);
      float4 c0 = *(const float4*)p1;
      float4 c1 = *(const float4*)(p1 + 4);
      u16 oa[8] = {f2bf(a0.x), f2bf(a0.y), f2bf(a0.z), f2bf(a0.w),
                   f2bf(a1.x), f2bf(a1.y), f2bf(a1.z), f2bf(a1.w)};
      u16 oc[8] = {f2bf(c0.x), f2bf(c0.y), f2bf(c0.z), f2bf(c0.w),
                   f2bf(c1.x), f2bf(c1.y), f2bf(c1.z), f2bf(c1.w)};
      short8v bf = *(const short8v*)&PlB[r0][kk];
      acc0 = __builtin_amdgcn_mfma_f32_16x16x32_bf16(*(const short8v*)oa, bf,
                                                     acc0, 0, 0, 0);
      acc1 = __builtin_amdgcn_mfma_f32_16x16x32_bf16(*(const short8v*)oc, bf,
                                                     acc1, 0, 0, 0);
    }
    int col = lane & 15;
    if (col < 8) {
      int i = i0 + col;
      int fb = fw + ((lane >> 4) << 2);
#pragma unroll
      for (int q = 0; q < 4; ++q) {
        size_t idx0 = (size_t)b * BS + (size_t)(fb + q) * 256 + i;
        size_t idx1 = (size_t)b * BS + (size_t)(fb + 16 + q) * 256 + i;
        out[idx0] = 1.f / (1.f + __expf(-acc0[q])) + xb2[(size_t)(fb + q) * 256 + i];
        out[idx1] = 1.f / (1.f + __expf(-acc1[q])) + xb2[(size_t)(fb + 16 + q) * 256 + i];
      }
    }
  }
}

extern "C" void kernel_launch(void* const* d_in, const int* in_sizes, int n_in,
                              void* d_out, int out_size, void* d_ws,
                              size_t ws_size, hipStream_t stream) {
  const float* x = (const float*)d_in[0];
  const int* adj = (const int*)d_in[1];
  const float* W = (const float*)d_in[2];
  const float* b_lin = (const float*)d_in[3];
  const float* a = (const float*)d_in[4];
  const float* bias = (const float*)d_in[5];
  float* out = (float*)d_out;

  float* L2p = (float*)d_ws;                 // 8*65536 f32
  u32* R2p = (u32*)(L2p + BB * BS);          // 8*32768 u32 (packed bf16 pairs)

  d1_proj<<<512, 256, 0, stream>>>(x, W, b_lin, a, L2p, R2p);
  d23_fused<<<256, 512, 0, stream>>>(R2p, L2p, a, adj, bias, x, out);
}